// Round 14
// baseline (197.510 us; speedup 1.0000x reference)
//
#include <hip/hip_runtime.h>

#define NN 50000
#define NNP 50016   // 1563 * 32, padded rows for the GEMM
#define NE 800000
#define DIN 64
#define HD 128
#define NBUK 196            // ceil(NN/256) coarse buckets (dst>>8)
#define SB 196              // ceil(NE/4096) scatter chunks
#define BCAP 12288          // build_csr LDS capacity (edges per bucket fast path)

typedef __attribute__((ext_vector_type(8))) short short8;
typedef __attribute__((ext_vector_type(4))) float f32x4;
typedef __attribute__((ext_vector_type(4))) unsigned short us4;
typedef __attribute__((ext_vector_type(8))) unsigned short us8;

__device__ __forceinline__ unsigned short f2bf(float f) {
    unsigned int u = __float_as_uint(f);
    u = (u + 0x7FFFu + ((u >> 16) & 1u)) >> 16;
    return (unsigned short)u;
}
__device__ __forceinline__ float bf2f(unsigned short u) {
    return __uint_as_float(((unsigned int)u) << 16);
}

// inclusive Hillis-Steele scan over a[256]; all 256 threads must execute
#define LDS_SCAN256(a, t)                                 \
    for (int off_ = 1; off_ < 256; off_ <<= 1) {          \
        int add_ = ((t) >= off_) ? (a)[(t) - off_] : 0;   \
        __syncthreads();                                  \
        (a)[t] += add_;                                   \
        __syncthreads();                                  \
    }

// ---------------- CSR via two-level LDS counting sort ----------------
// packed edge: (dst&255)<<24 | src  (src < 2^17); bucket id kept in LDS byte array.

__global__ __launch_bounds__(256) void bucket_count(const int* __restrict__ dst,
                                                    int* __restrict__ bcnt) {
    __shared__ int lc[256];
    int t = threadIdx.x;
    lc[t] = 0;
    __syncthreads();
    int base = blockIdx.x * 4096 + t * 16;
#pragma unroll
    for (int j = 0; j < 4; ++j) {
        int e = base + j * 4;
        if (e < NE) {
            int4 d = *(const int4*)(dst + e);
            atomicAdd(&lc[d.x >> 8], 1);
            atomicAdd(&lc[d.y >> 8], 1);
            atomicAdd(&lc[d.z >> 8], 1);
            atomicAdd(&lc[d.w >> 8], 1);
        }
    }
    __syncthreads();
    if (t < NBUK && lc[t] > 0) atomicAdd(&bcnt[t], lc[t]);
}

__global__ __launch_bounds__(256) void bucket_scan(const int* __restrict__ bcnt,
                                                   int* __restrict__ bbase,
                                                   int* __restrict__ rowptr) {
    __shared__ int sh[256];
    int t = threadIdx.x;
    int v = (t < NBUK) ? bcnt[t] : 0;
    sh[t] = v;
    __syncthreads();
    LDS_SCAN256(sh, t);
    if (t < NBUK) bbase[t] = sh[t] - v;   // exclusive
    if (t == NBUK - 1) bbase[NBUK] = sh[t];
    if (t == 0) rowptr[NN] = NE;
}

__global__ __launch_bounds__(256) void bucket_scatter(
    const int* __restrict__ src, const int* __restrict__ dst,
    const int* __restrict__ bbase, int* __restrict__ bfill,
    int* __restrict__ pairs) {
    __shared__ int cnt[256];
    __shared__ int incl[256];
    __shared__ int lfill[256];
    __shared__ int rung[256];
    __shared__ int buf[4096];
    __shared__ unsigned char bk[4096];
    int t = threadIdx.x;
    cnt[t] = 0;
    lfill[t] = 0;
    __syncthreads();
    int base = blockIdx.x * 4096 + t * 16;
#pragma unroll
    for (int j = 0; j < 4; ++j) {
        int e = base + j * 4;
        if (e < NE) {
            int4 d = *(const int4*)(dst + e);
            atomicAdd(&cnt[d.x >> 8], 1);
            atomicAdd(&cnt[d.y >> 8], 1);
            atomicAdd(&cnt[d.z >> 8], 1);
            atomicAdd(&cnt[d.w >> 8], 1);
        }
    }
    __syncthreads();
    incl[t] = cnt[t];
    __syncthreads();
    LDS_SCAN256(incl, t);
    int c = cnt[t];
    if (t < NBUK && c > 0) rung[t] = bbase[t] + atomicAdd(&bfill[t], c);
    __syncthreads();
#pragma unroll
    for (int j = 0; j < 4; ++j) {
        int e = base + j * 4;
        if (e < NE) {
            int4 s4 = *(const int4*)(src + e);
            int4 d4 = *(const int4*)(dst + e);
            int ss[4] = {s4.x, s4.y, s4.z, s4.w};
            int dd[4] = {d4.x, d4.y, d4.z, d4.w};
#pragma unroll
            for (int q = 0; q < 4; ++q) {
                int k = dd[q] >> 8;
                int p = (incl[k] - cnt[k]) + atomicAdd(&lfill[k], 1);
                buf[p] = ((dd[q] & 255) << 24) | ss[q];
                bk[p] = (unsigned char)k;
            }
        }
    }
    __syncthreads();
    int n = min(4096, NE - blockIdx.x * 4096);
    for (int i = t; i < n; i += 256) {
        int k = bk[i];
        pairs[rung[k] + (i - (incl[k] - cnt[k]))] = buf[i];
    }
}

__global__ __launch_bounds__(256) void build_csr(
    const int* __restrict__ pairs, const int* __restrict__ bbase,
    int* __restrict__ rowptr, float* __restrict__ invcnt,
    int* __restrict__ csr_src) {
    __shared__ int cnt[256];
    __shared__ int incl[256];
    __shared__ int lfill[256];
    __shared__ int sbuf[BCAP];
    int b = blockIdx.x, t = threadIdx.x;
    int pbeg = bbase[b], pend = bbase[b + 1];
    int sz = pend - pbeg;
    cnt[t] = 0;
    lfill[t] = 0;
    __syncthreads();
    for (int i = t; i < sz; i += 256)
        atomicAdd(&cnt[(unsigned)pairs[pbeg + i] >> 24], 1);
    __syncthreads();
    incl[t] = cnt[t];
    __syncthreads();
    LDS_SCAN256(incl, t);
    int node = b * 256 + t;
    int c = cnt[t];
    if (node < NN) {
        rowptr[node] = pbeg + incl[t] - c;
        invcnt[node] = 1.0f / (float)(c > 0 ? c : 1);
    }
    if (sz <= BCAP) {
        for (int i = t; i < sz; i += 256) {
            int pr = pairs[pbeg + i];
            int ld = (unsigned)pr >> 24;
            sbuf[(incl[ld] - cnt[ld]) + atomicAdd(&lfill[ld], 1)] = pr & 0xFFFFFF;
        }
        __syncthreads();
        for (int i = t; i < sz; i += 256) csr_src[pbeg + i] = sbuf[i];
    } else {  // safety fallback
        for (int i = t; i < sz; i += 256) {
            int pr = pairs[pbeg + i];
            int ld = (unsigned)pr >> 24;
            csr_src[pbeg + (incl[ld] - cnt[ld]) + atomicAdd(&lfill[ld], 1)] = pr & 0xFFFFFF;
        }
    }
}

// ---------------- prep: zero meta + pack weights + x -> bf16 Xbf[NNP][64] ----------------

__device__ __forceinline__ void pack_one(const float* Wl, const float* Wr, int D,
                                         unsigned short* Wpk, int i) {
    int j = i & 7;
    int lane = (i >> 3) & 63;
    int ct = (i >> 9) & 7;
    int ks = i >> 12;
    int k = ks * 32 + ((lane >> 4) << 3) + j;
    int c = ct * 16 + (lane & 15);
    float v = (k < D) ? Wl[c * D + k] : Wr[c * D + (k - D)];
    Wpk[i] = f2bf(v);
}

#define PACK_BLOCKS 320   // 81920/256
#define CONV_BLOCKS 3125  // NN*16/256

__global__ __launch_bounds__(256) void prep(
    const float* __restrict__ Wl0, const float* __restrict__ Wr0,
    const float* __restrict__ Wl1, const float* __restrict__ Wr1,
    const float* __restrict__ Wl2, const float* __restrict__ Wr2,
    unsigned short* __restrict__ Wpk0, unsigned short* __restrict__ Wpk1,
    unsigned short* __restrict__ Wpk2,
    const float* __restrict__ x, unsigned short* __restrict__ Xbf,
    int* __restrict__ meta) {
    const int S0 = 2 * DIN * HD;   // 16384
    const int S12 = 2 * HD * HD;   // 32768
    int b = blockIdx.x;
    int t = threadIdx.x;
    if (b < PACK_BLOCKS) {
        int i = b * 256 + t;
        if (i < S0) { pack_one(Wl0, Wr0, DIN, Wpk0, i); return; }
        int j = i - S0;
        if (j < S12) { pack_one(Wl1, Wr1, HD, Wpk1, j); return; }
        int m = j - S12;
        if (m < S12) pack_one(Wl2, Wr2, HD, Wpk2, m);
        return;
    }
    if (b < PACK_BLOCKS + CONV_BLOCKS) {
        // x f32 [NN][64] -> bf16 Xbf[NNP][64]
        int i = (b - PACK_BLOCKS) * 256 + t;   // < NN*16
        int row = i >> 4, c4 = i & 15;
        float4 v = ((const float4*)(x + (size_t)row * DIN))[c4];
        us4 o = {f2bf(v.x), f2bf(v.y), f2bf(v.z), f2bf(v.w)};
        *(us4*)(Xbf + (size_t)row * DIN + c4 * 4) = o;
        return;
    }
    // last block: zero meta (bcnt[256] + bfill[256]) — 256 threads cover 512 ints
    meta[t] = 0;
    meta[t + 256] = 0;
}

// ---------------- fused SAGE layer: gather-mean (LDS) + MFMA GEMM + bias + L2norm (+ReLU) ----------------
// Block = 32 nodes. Phase 1: gather-mean neighbor rows of Hin into LDS (XOR-swizzled 16B chunks).
// Phase 2: GEMM C[32x128] = [mean | h] x Wpk; mean half of A from LDS, h half from global Hin.
// D=64: half-wave per node (8 c8-lanes x 4 eg), 2 nodes parallel x 4 serial per wave.
// D=128: wave per node (16 c8-lanes x 4 eg), 8 serial per wave.

template <int D, bool RELU, bool F32OUT>
__global__ __launch_bounds__(256) void sage_layer(
    const unsigned short* __restrict__ Hin, const int* __restrict__ rowptr,
    const int* __restrict__ csr_src, const float* __restrict__ invcnt,
    const unsigned short* __restrict__ Wpk, const float* __restrict__ bias,
    float* __restrict__ outF, unsigned short* __restrict__ Hout) {
    constexpr int K = 2 * D;
    constexpr int NK = K / 32;
    constexpr int NKH = NK / 2;
    constexpr int NCH = D / 8;           // 16B chunks per mean row
    __shared__ unsigned short mean_lds[32 * D];
    __shared__ float rsum[2][32];

    int tid = threadIdx.x;
    int lane = tid & 63, w = tid >> 6;
    int n0 = blockIdx.x * 32;

    // ---- phase 1: gather-mean into LDS ----
    if (D == 128) {
        int c8 = lane & 15, eg = lane >> 4;
        const unsigned short* hb = Hin + (size_t)c8 * 8;
#pragma unroll
        for (int i = 0; i < 8; ++i) {
            int nl = w * 8 + i;
            int n = n0 + nl;
            float acc[8] = {};
            if (n < NN) {
                int beg = rowptr[n], end = rowptr[n + 1];
                int e = beg + eg;
                for (; e + 12 < end; e += 16) {  // 4-deep load pipeline
                    int i0 = csr_src[e], i1 = csr_src[e + 4];
                    int i2 = csr_src[e + 8], i3 = csr_src[e + 12];
                    us8 v0 = *(const us8*)(hb + (size_t)i0 * D);
                    us8 v1 = *(const us8*)(hb + (size_t)i1 * D);
                    us8 v2 = *(const us8*)(hb + (size_t)i2 * D);
                    us8 v3 = *(const us8*)(hb + (size_t)i3 * D);
#pragma unroll
                    for (int j = 0; j < 8; ++j)
                        acc[j] += (bf2f(v0[j]) + bf2f(v1[j])) + (bf2f(v2[j]) + bf2f(v3[j]));
                }
                for (; e < end; e += 4) {
                    us8 v0 = *(const us8*)(hb + (size_t)csr_src[e] * D);
#pragma unroll
                    for (int j = 0; j < 8; ++j) acc[j] += bf2f(v0[j]);
                }
#pragma unroll
                for (int j = 0; j < 8; ++j) {
                    acc[j] += __shfl_xor(acc[j], 16, 64);
                    acc[j] += __shfl_xor(acc[j], 32, 64);
                }
            }
            if (eg == 0) {
                float ic = (n < NN) ? invcnt[n] : 0.f;
                us8 o;
#pragma unroll
                for (int j = 0; j < 8; ++j) o[j] = f2bf(acc[j] * ic);
                *(us8*)&mean_lds[(nl * NCH + (c8 ^ (nl & 7))) * 8] = o;
            }
        }
    } else {  // D == 64
        int c8 = lane & 7, eg = (lane >> 3) & 3, half = lane >> 5;
        const unsigned short* hb = Hin + (size_t)c8 * 8;
#pragma unroll
        for (int i = 0; i < 4; ++i) {
            int nl = w * 8 + i * 2 + half;
            int n = n0 + nl;
            float acc[8] = {};
            if (n < NN) {
                int beg = rowptr[n], end = rowptr[n + 1];
                int e = beg + eg;
                for (; e + 12 < end; e += 16) {  // 4-deep load pipeline
                    int i0 = csr_src[e], i1 = csr_src[e + 4];
                    int i2 = csr_src[e + 8], i3 = csr_src[e + 12];
                    us8 v0 = *(const us8*)(hb + (size_t)i0 * D);
                    us8 v1 = *(const us8*)(hb + (size_t)i1 * D);
                    us8 v2 = *(const us8*)(hb + (size_t)i2 * D);
                    us8 v3 = *(const us8*)(hb + (size_t)i3 * D);
#pragma unroll
                    for (int j = 0; j < 8; ++j)
                        acc[j] += (bf2f(v0[j]) + bf2f(v1[j])) + (bf2f(v2[j]) + bf2f(v3[j]));
                }
                for (; e < end; e += 4) {
                    us8 v0 = *(const us8*)(hb + (size_t)csr_src[e] * D);
#pragma unroll
                    for (int j = 0; j < 8; ++j) acc[j] += bf2f(v0[j]);
                }
#pragma unroll
                for (int j = 0; j < 8; ++j) {
                    acc[j] += __shfl_xor(acc[j], 8, 64);
                    acc[j] += __shfl_xor(acc[j], 16, 64);
                }
            }
            if (eg == 0) {
                float ic = (n < NN) ? invcnt[n] : 0.f;
                us8 o;
#pragma unroll
                for (int j = 0; j < 8; ++j) o[j] = f2bf(acc[j] * ic);
                *(us8*)&mean_lds[(nl * NCH + (c8 ^ (nl & 7))) * 8] = o;
            }
        }
    }
    __syncthreads();

    // ---- phase 2: MFMA GEMM ----
    int rg = w >> 1, cg = w & 1;
    int r0 = n0 + rg * 16;
    int row_l = lane & 15, kb = lane >> 4;
    int lrow = rg * 16 + row_l;

    const unsigned short* Hrow = Hin + (size_t)(r0 + row_l) * D + kb * 8;
    const unsigned short* Wp = Wpk + ((size_t)(cg * 4) * 64 + lane) * 8;

    f32x4 acc[4] = {{0.f, 0.f, 0.f, 0.f}, {0.f, 0.f, 0.f, 0.f},
                    {0.f, 0.f, 0.f, 0.f}, {0.f, 0.f, 0.f, 0.f}};
#pragma unroll
    for (int ks = 0; ks < NK; ++ks) {
        short8 a;
        if (ks < NKH) {
            int chunk = ks * 4 + kb;
            a = *(const short8*)&mean_lds[(lrow * NCH + (chunk ^ (lrow & 7))) * 8];
        } else {
            a = *(const short8*)(Hrow + (ks - NKH) * 32);
        }
#pragma unroll
        for (int t = 0; t < 4; ++t) {
            short8 b = *(const short8*)(Wp + ((size_t)ks * 8 + t) * 64 * 8);
            acc[t] = __builtin_amdgcn_mfma_f32_16x16x32_bf16(a, b, acc[t], 0, 0, 0);
        }
    }

    float sq[4] = {0.f, 0.f, 0.f, 0.f};
#pragma unroll
    for (int t = 0; t < 4; ++t) {
        float bv = bias[cg * 64 + t * 16 + row_l];
#pragma unroll
        for (int r = 0; r < 4; ++r) {
            acc[t][r] += bv;
            sq[r] = fmaf(acc[t][r], acc[t][r], sq[r]);
        }
    }
#pragma unroll
    for (int off = 1; off < 16; off <<= 1)
#pragma unroll
        for (int r = 0; r < 4; ++r) sq[r] += __shfl_xor(sq[r], off, 64);

    if (row_l == 0) {
#pragma unroll
        for (int r = 0; r < 4; ++r) rsum[cg][rg * 16 + kb * 4 + r] = sq[r];
    }
    __syncthreads();

    int rbase = rg * 16 + kb * 4;
#pragma unroll
    for (int r = 0; r < 4; ++r) {
        int row = r0 + kb * 4 + r;
        if (row >= NN) continue;
        float n2 = rsum[0][rbase + r] + rsum[1][rbase + r];
        float inv = 1.0f / fmaxf(sqrtf(n2), 1e-12f);
#pragma unroll
        for (int t = 0; t < 4; ++t) {
            float v = acc[t][r] * inv;
            if (RELU) v = fmaxf(v, 0.f);
            int c = cg * 64 + t * 16 + row_l;
            if (F32OUT) outF[(size_t)row * HD + c] = v;
            else Hout[(size_t)row * HD + c] = f2bf(v);
        }
    }
}

// ---------------- launch ----------------

static inline size_t align256(size_t x) { return (x + 255) & ~(size_t)255; }

extern "C" void kernel_launch(void* const* d_in, const int* in_sizes, int n_in,
                              void* d_out, int out_size, void* d_ws, size_t ws_size,
                              hipStream_t stream) {
    const float* x   = (const float*)d_in[0];
    const int*   ei  = (const int*)d_in[1];
    const float* Wl0 = (const float*)d_in[2];
    const float* bl0 = (const float*)d_in[3];
    const float* Wr0 = (const float*)d_in[4];
    const float* Wl1 = (const float*)d_in[5];
    const float* bl1 = (const float*)d_in[6];
    const float* Wr1 = (const float*)d_in[7];
    const float* Wl2 = (const float*)d_in[8];
    const float* bl2 = (const float*)d_in[9];
    const float* Wr2 = (const float*)d_in[10];

    const int* src = ei;
    const int* dst = ei + NE;

    // workspace carve-up
    char* p = (char*)d_ws;
    size_t off = 0;
    int* meta = (int*)(p + off);            off = align256(off + 512 * 4);
    int* bbase = (int*)(p + off);           off = align256(off + 256 * 4);
    int* rowptr = (int*)(p + off);          off = align256(off + (size_t)(NN + 1) * 4);
    int* csr_src = (int*)(p + off);         off = align256(off + (size_t)NE * 4);
    float* invcnt = (float*)(p + off);      off = align256(off + (size_t)NN * 4);
    int* pairs = (int*)(p + off);           off = align256(off + (size_t)NE * 4);
    unsigned short* Xbf = (unsigned short*)(p + off);  off = align256(off + (size_t)NNP * DIN * 2);
    unsigned short* H0 = (unsigned short*)(p + off);   off = align256(off + (size_t)NNP * HD * 2);
    unsigned short* H1 = (unsigned short*)(p + off);   off = align256(off + (size_t)NNP * HD * 2);
    unsigned short* Wpk0 = (unsigned short*)(p + off); off = align256(off + (size_t)2 * DIN * HD * 2);
    unsigned short* Wpk1 = (unsigned short*)(p + off); off = align256(off + (size_t)2 * HD * HD * 2);
    unsigned short* Wpk2 = (unsigned short*)(p + off); off = align256(off + (size_t)2 * HD * HD * 2);
    (void)ws_size; (void)n_in; (void)in_sizes; (void)out_size;

    int* bcnt = meta;
    int* bfill = meta + 256;
    float* out = (float*)d_out;

    // prep (packs weights, converts x -> Xbf, zeroes meta)
    prep<<<PACK_BLOCKS + CONV_BLOCKS + 1, 256, 0, stream>>>(
        Wl0, Wr0, Wl1, Wr1, Wl2, Wr2, Wpk0, Wpk1, Wpk2, x, Xbf, meta);

    // CSR build: two-level LDS counting sort
    bucket_count<<<SB, 256, 0, stream>>>(dst, bcnt);
    bucket_scan<<<1, 256, 0, stream>>>(bcnt, bbase, rowptr);
    bucket_scatter<<<SB, 256, 0, stream>>>(src, dst, bbase, bfill, pairs);
    build_csr<<<NBUK, 256, 0, stream>>>(pairs, bbase, rowptr, invcnt, csr_src);

    const int LG = NNP / 32;  // 1563

    // fused layers (gather -> LDS -> GEMM); ping-pong h buffers, no aliasing
    sage_layer<DIN, true, false><<<LG, 256, 0, stream>>>(
        Xbf, rowptr, csr_src, invcnt, Wpk0, bl0, nullptr, H0);
    sage_layer<HD, true, false><<<LG, 256, 0, stream>>>(
        H0, rowptr, csr_src, invcnt, Wpk1, bl1, nullptr, H1);
    sage_layer<HD, false, true><<<LG, 256, 0, stream>>>(
        H1, rowptr, csr_src, invcnt, Wpk2, bl2, out, nullptr);
}

// Round 15
// 184.570 us; speedup vs baseline: 1.0701x; 1.0701x over previous
//
#include <hip/hip_runtime.h>

#define NN 50000
#define NNP 50016   // 1563 * 32, padded rows for the GEMM
#define NE 800000
#define DIN 64
#define HD 128
#define NBUK 196            // ceil(NN/256) coarse buckets (dst>>8)
#define SB 196              // ceil(NE/4096) scatter chunks
#define BCAP 12288          // build_csr LDS capacity (edges per bucket fast path)

typedef __attribute__((ext_vector_type(8))) short short8;
typedef __attribute__((ext_vector_type(4))) float f32x4;
typedef __attribute__((ext_vector_type(4))) unsigned short us4;
typedef __attribute__((ext_vector_type(8))) unsigned short us8;

__device__ __forceinline__ unsigned short f2bf(float f) {
    unsigned int u = __float_as_uint(f);
    u = (u + 0x7FFFu + ((u >> 16) & 1u)) >> 16;
    return (unsigned short)u;
}
__device__ __forceinline__ float bf2f(unsigned short u) {
    return __uint_as_float(((unsigned int)u) << 16);
}

// inclusive Hillis-Steele scan over a[256]; all 256 threads must execute
#define LDS_SCAN256(a, t)                                 \
    for (int off_ = 1; off_ < 256; off_ <<= 1) {          \
        int add_ = ((t) >= off_) ? (a)[(t) - off_] : 0;   \
        __syncthreads();                                  \
        (a)[t] += add_;                                   \
        __syncthreads();                                  \
    }

// ---------------- CSR via two-level LDS counting sort ----------------
// packed edge: (dst&255)<<24 | src  (src < 2^17); bucket id kept in LDS byte array.

__global__ __launch_bounds__(256) void bucket_count(const int* __restrict__ dst,
                                                    int* __restrict__ bcnt) {
    __shared__ int lc[256];
    int t = threadIdx.x;
    lc[t] = 0;
    __syncthreads();
    int base = blockIdx.x * 4096 + t * 16;
#pragma unroll
    for (int j = 0; j < 4; ++j) {
        int e = base + j * 4;
        if (e < NE) {
            int4 d = *(const int4*)(dst + e);
            atomicAdd(&lc[d.x >> 8], 1);
            atomicAdd(&lc[d.y >> 8], 1);
            atomicAdd(&lc[d.z >> 8], 1);
            atomicAdd(&lc[d.w >> 8], 1);
        }
    }
    __syncthreads();
    if (t < NBUK && lc[t] > 0) atomicAdd(&bcnt[t], lc[t]);
}

__global__ __launch_bounds__(256) void bucket_scan(const int* __restrict__ bcnt,
                                                   int* __restrict__ bbase,
                                                   int* __restrict__ rowptr) {
    __shared__ int sh[256];
    int t = threadIdx.x;
    int v = (t < NBUK) ? bcnt[t] : 0;
    sh[t] = v;
    __syncthreads();
    LDS_SCAN256(sh, t);
    if (t < NBUK) bbase[t] = sh[t] - v;   // exclusive
    if (t == NBUK - 1) bbase[NBUK] = sh[t];
    if (t == 0) rowptr[NN] = NE;
}

__global__ __launch_bounds__(256) void bucket_scatter(
    const int* __restrict__ src, const int* __restrict__ dst,
    const int* __restrict__ bbase, int* __restrict__ bfill,
    int* __restrict__ pairs) {
    __shared__ int cnt[256];
    __shared__ int incl[256];
    __shared__ int lfill[256];
    __shared__ int rung[256];
    __shared__ int buf[4096];
    __shared__ unsigned char bk[4096];
    int t = threadIdx.x;
    cnt[t] = 0;
    lfill[t] = 0;
    __syncthreads();
    int base = blockIdx.x * 4096 + t * 16;
#pragma unroll
    for (int j = 0; j < 4; ++j) {
        int e = base + j * 4;
        if (e < NE) {
            int4 d = *(const int4*)(dst + e);
            atomicAdd(&cnt[d.x >> 8], 1);
            atomicAdd(&cnt[d.y >> 8], 1);
            atomicAdd(&cnt[d.z >> 8], 1);
            atomicAdd(&cnt[d.w >> 8], 1);
        }
    }
    __syncthreads();
    incl[t] = cnt[t];
    __syncthreads();
    LDS_SCAN256(incl, t);
    int c = cnt[t];
    if (t < NBUK && c > 0) rung[t] = bbase[t] + atomicAdd(&bfill[t], c);
    __syncthreads();
#pragma unroll
    for (int j = 0; j < 4; ++j) {
        int e = base + j * 4;
        if (e < NE) {
            int4 s4 = *(const int4*)(src + e);
            int4 d4 = *(const int4*)(dst + e);
            int ss[4] = {s4.x, s4.y, s4.z, s4.w};
            int dd[4] = {d4.x, d4.y, d4.z, d4.w};
#pragma unroll
            for (int q = 0; q < 4; ++q) {
                int k = dd[q] >> 8;
                int p = (incl[k] - cnt[k]) + atomicAdd(&lfill[k], 1);
                buf[p] = ((dd[q] & 255) << 24) | ss[q];
                bk[p] = (unsigned char)k;
            }
        }
    }
    __syncthreads();
    int n = min(4096, NE - blockIdx.x * 4096);
    for (int i = t; i < n; i += 256) {
        int k = bk[i];
        pairs[rung[k] + (i - (incl[k] - cnt[k]))] = buf[i];
    }
}

__global__ __launch_bounds__(256) void build_csr(
    const int* __restrict__ pairs, const int* __restrict__ bbase,
    int* __restrict__ rowptr, float* __restrict__ invcnt,
    int* __restrict__ csr_src) {
    __shared__ int cnt[256];
    __shared__ int incl[256];
    __shared__ int lfill[256];
    __shared__ int sbuf[BCAP];
    int b = blockIdx.x, t = threadIdx.x;
    int pbeg = bbase[b], pend = bbase[b + 1];
    int sz = pend - pbeg;
    cnt[t] = 0;
    lfill[t] = 0;
    __syncthreads();
    for (int i = t; i < sz; i += 256)
        atomicAdd(&cnt[(unsigned)pairs[pbeg + i] >> 24], 1);
    __syncthreads();
    incl[t] = cnt[t];
    __syncthreads();
    LDS_SCAN256(incl, t);
    int node = b * 256 + t;
    int c = cnt[t];
    if (node < NN) {
        rowptr[node] = pbeg + incl[t] - c;
        invcnt[node] = 1.0f / (float)(c > 0 ? c : 1);
    }
    if (sz <= BCAP) {
        for (int i = t; i < sz; i += 256) {
            int pr = pairs[pbeg + i];
            int ld = (unsigned)pr >> 24;
            sbuf[(incl[ld] - cnt[ld]) + atomicAdd(&lfill[ld], 1)] = pr & 0xFFFFFF;
        }
        __syncthreads();
        for (int i = t; i < sz; i += 256) csr_src[pbeg + i] = sbuf[i];
    } else {  // safety fallback
        for (int i = t; i < sz; i += 256) {
            int pr = pairs[pbeg + i];
            int ld = (unsigned)pr >> 24;
            csr_src[pbeg + (incl[ld] - cnt[ld]) + atomicAdd(&lfill[ld], 1)] = pr & 0xFFFFFF;
        }
    }
}

// ---------------- prep: zero meta + pack weights + x -> bf16 into A0 h-half ----------------

__device__ __forceinline__ void pack_one(const float* Wl, const float* Wr, int D,
                                         unsigned short* Wpk, int i) {
    int j = i & 7;
    int lane = (i >> 3) & 63;
    int ct = (i >> 9) & 7;
    int ks = i >> 12;
    int k = ks * 32 + ((lane >> 4) << 3) + j;
    int c = ct * 16 + (lane & 15);
    float v = (k < D) ? Wl[c * D + k] : Wr[c * D + (k - D)];
    Wpk[i] = f2bf(v);
}

#define PACK_BLOCKS 320   // 81920/256
#define CONV_BLOCKS 3125  // NN*16/256

__global__ __launch_bounds__(256) void prep(
    const float* __restrict__ Wl0, const float* __restrict__ Wr0,
    const float* __restrict__ Wl1, const float* __restrict__ Wr1,
    const float* __restrict__ Wl2, const float* __restrict__ Wr2,
    unsigned short* __restrict__ Wpk0, unsigned short* __restrict__ Wpk1,
    unsigned short* __restrict__ Wpk2,
    const float* __restrict__ x, unsigned short* __restrict__ A0,
    int* __restrict__ meta) {
    const int S0 = 2 * DIN * HD;   // 16384
    const int S12 = 2 * HD * HD;   // 32768
    int b = blockIdx.x;
    int t = threadIdx.x;
    if (b < PACK_BLOCKS) {
        int i = b * 256 + t;
        if (i < S0) { pack_one(Wl0, Wr0, DIN, Wpk0, i); return; }
        int j = i - S0;
        if (j < S12) { pack_one(Wl1, Wr1, HD, Wpk1, j); return; }
        int m = j - S12;
        if (m < S12) pack_one(Wl2, Wr2, HD, Wpk2, m);
        return;
    }
    if (b < PACK_BLOCKS + CONV_BLOCKS) {
        // x f32 [NN][64] -> bf16 into A0[:, 64:128] (row stride 128 shorts)
        int i = (b - PACK_BLOCKS) * 256 + t;   // < NN*16
        int row = i >> 4, c4 = i & 15;
        float4 v = ((const float4*)(x + (size_t)row * DIN))[c4];
        us4 o = {f2bf(v.x), f2bf(v.y), f2bf(v.z), f2bf(v.w)};
        *(us4*)(A0 + (size_t)row * 128 + 64 + c4 * 4) = o;
        return;
    }
    // last block: zero meta (bcnt[256] + bfill[256]) — 256 threads cover 512 ints
    meta[t] = 0;
    meta[t + 256] = 0;
}

// ---------------- gather-mean layer 0: 16 lanes/node, 8-deep pipeline ----------------
// 16 nodes/block; 16 lanes/node = 2 edge-groups x 8 ch-lanes (us8 = 64ch).

__global__ __launch_bounds__(256) void gather_mean_x(
    const int* __restrict__ rowptr, const int* __restrict__ csr_src,
    const float* __restrict__ invcnt, unsigned short* __restrict__ A0) {
    int tid = threadIdx.x;
    int n = blockIdx.x * 16 + (tid >> 4);
    int c8 = tid & 7;
    int eg = (tid >> 3) & 1;
    int beg = rowptr[n], end = rowptr[n + 1];
    float acc[8] = {};
    const unsigned short* hb = A0 + 64 + (size_t)c8 * 8;
    int e = beg + eg;
    for (; e + 14 < end; e += 16) {  // 8-deep load pipeline (stride 2)
        int i0 = csr_src[e],      i1 = csr_src[e + 2];
        int i2 = csr_src[e + 4],  i3 = csr_src[e + 6];
        int i4 = csr_src[e + 8],  i5 = csr_src[e + 10];
        int i6 = csr_src[e + 12], i7 = csr_src[e + 14];
        us8 v0 = *(const us8*)(hb + (size_t)i0 * 128);
        us8 v1 = *(const us8*)(hb + (size_t)i1 * 128);
        us8 v2 = *(const us8*)(hb + (size_t)i2 * 128);
        us8 v3 = *(const us8*)(hb + (size_t)i3 * 128);
        us8 v4 = *(const us8*)(hb + (size_t)i4 * 128);
        us8 v5 = *(const us8*)(hb + (size_t)i5 * 128);
        us8 v6 = *(const us8*)(hb + (size_t)i6 * 128);
        us8 v7 = *(const us8*)(hb + (size_t)i7 * 128);
#pragma unroll
        for (int j = 0; j < 8; ++j)
            acc[j] += ((bf2f(v0[j]) + bf2f(v1[j])) + (bf2f(v2[j]) + bf2f(v3[j]))) +
                      ((bf2f(v4[j]) + bf2f(v5[j])) + (bf2f(v6[j]) + bf2f(v7[j])));
    }
    for (; e < end; e += 2) {
        us8 v0 = *(const us8*)(hb + (size_t)csr_src[e] * 128);
#pragma unroll
        for (int j = 0; j < 8; ++j) acc[j] += bf2f(v0[j]);
    }
#pragma unroll
    for (int j = 0; j < 8; ++j) acc[j] += __shfl_xor(acc[j], 8, 64);
    if (eg == 0) {
        float ic = invcnt[n];
        us8 o;
#pragma unroll
        for (int j = 0; j < 8; ++j) o[j] = f2bf(acc[j] * ic);
        *(us8*)(A0 + (size_t)n * 128 + c8 * 8) = o;
    }
}

// ---------------- gather-mean layers 1,2: 32 lanes/node, 8-deep pipeline ----------------
// 8 nodes/block; 32 lanes/node = 2 edge-groups x 16 ch-lanes (us8 = 128ch).

__global__ __launch_bounds__(256) void gather_mean_h(
    const unsigned short* __restrict__ A12, const int* __restrict__ rowptr,
    const int* __restrict__ csr_src, const float* __restrict__ invcnt,
    unsigned short* __restrict__ Am) {
    int tid = threadIdx.x;
    int n = blockIdx.x * 8 + (tid >> 5);
    int c8 = tid & 15;
    int eg = (tid >> 4) & 1;
    int beg = rowptr[n], end = rowptr[n + 1];
    float acc[8] = {};
    const unsigned short* hb = A12 + 128 + (size_t)c8 * 8;
    int e = beg + eg;
    for (; e + 14 < end; e += 16) {  // 8-deep load pipeline (stride 2)
        int i0 = csr_src[e],      i1 = csr_src[e + 2];
        int i2 = csr_src[e + 4],  i3 = csr_src[e + 6];
        int i4 = csr_src[e + 8],  i5 = csr_src[e + 10];
        int i6 = csr_src[e + 12], i7 = csr_src[e + 14];
        us8 v0 = *(const us8*)(hb + (size_t)i0 * 256);
        us8 v1 = *(const us8*)(hb + (size_t)i1 * 256);
        us8 v2 = *(const us8*)(hb + (size_t)i2 * 256);
        us8 v3 = *(const us8*)(hb + (size_t)i3 * 256);
        us8 v4 = *(const us8*)(hb + (size_t)i4 * 256);
        us8 v5 = *(const us8*)(hb + (size_t)i5 * 256);
        us8 v6 = *(const us8*)(hb + (size_t)i6 * 256);
        us8 v7 = *(const us8*)(hb + (size_t)i7 * 256);
#pragma unroll
        for (int j = 0; j < 8; ++j)
            acc[j] += ((bf2f(v0[j]) + bf2f(v1[j])) + (bf2f(v2[j]) + bf2f(v3[j]))) +
                      ((bf2f(v4[j]) + bf2f(v5[j])) + (bf2f(v6[j]) + bf2f(v7[j])));
    }
    for (; e < end; e += 2) {
        us8 v0 = *(const us8*)(hb + (size_t)csr_src[e] * 256);
#pragma unroll
        for (int j = 0; j < 8; ++j) acc[j] += bf2f(v0[j]);
    }
#pragma unroll
    for (int j = 0; j < 8; ++j) acc[j] += __shfl_xor(acc[j], 16, 64);
    if (eg == 0) {
        float ic = invcnt[n];
        us8 o;
#pragma unroll
        for (int j = 0; j < 8; ++j) o[j] = f2bf(acc[j] * ic);
        *(us8*)(Am + (size_t)n * 256 + c8 * 8) = o;
    }
}

// ---------------- fused MFMA GEMM + bias + L2 norm + (ReLU) ----------------

template <int K, bool RELU, bool F32OUT, bool BF16H>
__global__ __launch_bounds__(256) void linear_mfma(
    const unsigned short* __restrict__ A, const unsigned short* __restrict__ Wpk,
    const float* __restrict__ bias, float* __restrict__ outF,
    unsigned short* __restrict__ Hn /* h-part base (stride 256) */) {
    constexpr int NK = K / 32;
    __shared__ float rsum[2][32];
    int tid = threadIdx.x;
    int lane = tid & 63, w = tid >> 6;
    int rg = w >> 1, cg = w & 1;
    int r0 = blockIdx.x * 32 + rg * 16;
    int row_l = lane & 15, kb = lane >> 4;

    const unsigned short* Arow = A + (size_t)(r0 + row_l) * K + kb * 8;
    const unsigned short* Wp = Wpk + ((size_t)(cg * 4) * 64 + lane) * 8;

    f32x4 acc[4] = {{0.f, 0.f, 0.f, 0.f}, {0.f, 0.f, 0.f, 0.f},
                    {0.f, 0.f, 0.f, 0.f}, {0.f, 0.f, 0.f, 0.f}};
#pragma unroll
    for (int ks = 0; ks < NK; ++ks) {
        short8 a = *(const short8*)(Arow + ks * 32);
#pragma unroll
        for (int t = 0; t < 4; ++t) {
            short8 b = *(const short8*)(Wp + ((size_t)ks * 8 + t) * 64 * 8);
            acc[t] = __builtin_amdgcn_mfma_f32_16x16x32_bf16(a, b, acc[t], 0, 0, 0);
        }
    }

    float sq[4] = {0.f, 0.f, 0.f, 0.f};
#pragma unroll
    for (int t = 0; t < 4; ++t) {
        float bv = bias[cg * 64 + t * 16 + row_l];
#pragma unroll
        for (int r = 0; r < 4; ++r) {
            acc[t][r] += bv;
            sq[r] = fmaf(acc[t][r], acc[t][r], sq[r]);
        }
    }
#pragma unroll
    for (int off = 1; off < 16; off <<= 1)
#pragma unroll
        for (int r = 0; r < 4; ++r) sq[r] += __shfl_xor(sq[r], off, 64);

    if (row_l == 0) {
#pragma unroll
        for (int r = 0; r < 4; ++r) rsum[cg][rg * 16 + kb * 4 + r] = sq[r];
    }
    __syncthreads();  // also orders all A reads before the BF16H in-place writes

    int rbase = rg * 16 + kb * 4;
#pragma unroll
    for (int r = 0; r < 4; ++r) {
        int row = r0 + kb * 4 + r;
        if (row >= NN) continue;
        float n2 = rsum[0][rbase + r] + rsum[1][rbase + r];
        float inv = 1.0f / fmaxf(sqrtf(n2), 1e-12f);
#pragma unroll
        for (int t = 0; t < 4; ++t) {
            float v = acc[t][r] * inv;
            if (RELU) v = fmaxf(v, 0.f);
            int c = cg * 64 + t * 16 + row_l;
            if (F32OUT) outF[(size_t)row * HD + c] = v;
            if (BF16H) Hn[(size_t)row * 256 + c] = f2bf(v);
        }
    }
}

// ---------------- launch ----------------

static inline size_t align256(size_t x) { return (x + 255) & ~(size_t)255; }

extern "C" void kernel_launch(void* const* d_in, const int* in_sizes, int n_in,
                              void* d_out, int out_size, void* d_ws, size_t ws_size,
                              hipStream_t stream) {
    const float* x   = (const float*)d_in[0];
    const int*   ei  = (const int*)d_in[1];
    const float* Wl0 = (const float*)d_in[2];
    const float* bl0 = (const float*)d_in[3];
    const float* Wr0 = (const float*)d_in[4];
    const float* Wl1 = (const float*)d_in[5];
    const float* bl1 = (const float*)d_in[6];
    const float* Wr1 = (const float*)d_in[7];
    const float* Wl2 = (const float*)d_in[8];
    const float* bl2 = (const float*)d_in[9];
    const float* Wr2 = (const float*)d_in[10];

    const int* src = ei;
    const int* dst = ei + NE;

    // workspace carve-up
    char* p = (char*)d_ws;
    size_t off = 0;
    int* meta = (int*)(p + off);            off = align256(off + 512 * 4);
    int* bbase = (int*)(p + off);           off = align256(off + 256 * 4);
    int* rowptr = (int*)(p + off);          off = align256(off + (size_t)(NN + 1) * 4);
    int* csr_src = (int*)(p + off);         off = align256(off + (size_t)NE * 4);
    float* invcnt = (float*)(p + off);      off = align256(off + (size_t)NN * 4);
    int* pairs = (int*)(p + off);           off = align256(off + (size_t)NE * 4);
    unsigned short* A0 = (unsigned short*)(p + off);   off = align256(off + (size_t)NNP * 128 * 2);
    unsigned short* A12 = (unsigned short*)(p + off);  off = align256(off + (size_t)NNP * 256 * 2);
    unsigned short* Wpk0 = (unsigned short*)(p + off); off = align256(off + (size_t)2 * DIN * HD * 2);
    unsigned short* Wpk1 = (unsigned short*)(p + off); off = align256(off + (size_t)2 * HD * HD * 2);
    unsigned short* Wpk2 = (unsigned short*)(p + off); off = align256(off + (size_t)2 * HD * HD * 2);
    (void)ws_size; (void)n_in; (void)in_sizes; (void)out_size;

    int* bcnt = meta;
    int* bfill = meta + 256;
    float* out = (float*)d_out;

    // prep first (packs weights, converts x, zeroes meta — all independent of CSR)
    prep<<<PACK_BLOCKS + CONV_BLOCKS + 1, 256, 0, stream>>>(
        Wl0, Wr0, Wl1, Wr1, Wl2, Wr2, Wpk0, Wpk1, Wpk2, x, A0, meta);

    // CSR build: two-level LDS counting sort (packed pairs)
    bucket_count<<<SB, 256, 0, stream>>>(dst, bcnt);
    bucket_scan<<<1, 256, 0, stream>>>(bcnt, bbase, rowptr);
    bucket_scatter<<<SB, 256, 0, stream>>>(src, dst, bbase, bfill, pairs);
    build_csr<<<NBUK, 256, 0, stream>>>(pairs, bbase, rowptr, invcnt, csr_src);

    const int LG = NNP / 32;     // 1563
    const int GX = NN / 16;      // 3125
    const int GH = NN / 8;       // 6250

    // layer 0: gather bf16 x rows -> A0 mean part; GEMM K=128 -> h0 bf16 into A12[:,128:256]
    gather_mean_x<<<GX, 256, 0, stream>>>(rowptr, csr_src, invcnt, A0);
    linear_mfma<2 * DIN, true, false, true><<<LG, 256, 0, stream>>>(
        A0, Wpk0, bl0, nullptr, A12 + 128);

    // layer 1: gather h0 -> A12 mean part; GEMM K=256 -> h1 bf16 (row-exclusive in-place)
    gather_mean_h<<<GH, 256, 0, stream>>>(A12, rowptr, csr_src, invcnt, A12);
    linear_mfma<2 * HD, true, false, true><<<LG, 256, 0, stream>>>(
        A12, Wpk1, bl1, nullptr, A12 + 128);

    // layer 2: gather h1 -> A12 mean part; GEMM K=256 -> f32 d_out
    gather_mean_h<<<GH, 256, 0, stream>>>(A12, rowptr, csr_src, invcnt, A12);
    linear_mfma<2 * HD, false, true, false><<<LG, 256, 0, stream>>>(
        A12, Wpk2, bl2, out, nullptr);
}

// Round 16
// 154.635 us; speedup vs baseline: 1.2773x; 1.1936x over previous
//
#include <hip/hip_runtime.h>

#define NN 50000
#define NNP 50016   // 1563 * 32, padded rows for the GEMM
#define NE 800000
#define DIN 64
#define HD 128
#define NBUK 196            // ceil(NN/256) coarse buckets (dst>>8)
#define SB 196              // ceil(NE/4096) scatter chunks
#define BCAP 12288          // build_csr LDS capacity (edges per bucket fast path)

typedef __attribute__((ext_vector_type(8))) short short8;
typedef __attribute__((ext_vector_type(4))) float f32x4;
typedef __attribute__((ext_vector_type(4))) unsigned short us4;
typedef __attribute__((ext_vector_type(8))) unsigned short us8;

__device__ __forceinline__ unsigned short f2bf(float f) {
    unsigned int u = __float_as_uint(f);
    u = (u + 0x7FFFu + ((u >> 16) & 1u)) >> 16;
    return (unsigned short)u;
}
__device__ __forceinline__ float bf2f(unsigned short u) {
    return __uint_as_float(((unsigned int)u) << 16);
}

// inclusive Hillis-Steele scan over a[256]; all 256 threads must execute
#define LDS_SCAN256(a, t)                                 \
    for (int off_ = 1; off_ < 256; off_ <<= 1) {          \
        int add_ = ((t) >= off_) ? (a)[(t) - off_] : 0;   \
        __syncthreads();                                  \
        (a)[t] += add_;                                   \
        __syncthreads();                                  \
    }

// ---------------- CSR via two-level LDS counting sort ----------------
// packed edge: (dst&255)<<24 | src  (src < 2^17); bucket id kept in LDS byte array.

__global__ __launch_bounds__(256) void bucket_count(const int* __restrict__ dst,
                                                    int* __restrict__ bcnt) {
    __shared__ int lc[256];
    int t = threadIdx.x;
    lc[t] = 0;
    __syncthreads();
    int base = blockIdx.x * 4096 + t * 16;
#pragma unroll
    for (int j = 0; j < 4; ++j) {
        int e = base + j * 4;
        if (e < NE) {
            int4 d = *(const int4*)(dst + e);
            atomicAdd(&lc[d.x >> 8], 1);
            atomicAdd(&lc[d.y >> 8], 1);
            atomicAdd(&lc[d.z >> 8], 1);
            atomicAdd(&lc[d.w >> 8], 1);
        }
    }
    __syncthreads();
    if (t < NBUK && lc[t] > 0) atomicAdd(&bcnt[t], lc[t]);
}

__global__ __launch_bounds__(256) void bucket_scan(const int* __restrict__ bcnt,
                                                   int* __restrict__ bbase,
                                                   int* __restrict__ rowptr) {
    __shared__ int sh[256];
    int t = threadIdx.x;
    int v = (t < NBUK) ? bcnt[t] : 0;
    sh[t] = v;
    __syncthreads();
    LDS_SCAN256(sh, t);
    if (t < NBUK) bbase[t] = sh[t] - v;   // exclusive
    if (t == NBUK - 1) bbase[NBUK] = sh[t];
    if (t == 0) rowptr[NN] = NE;
}

__global__ __launch_bounds__(256) void bucket_scatter(
    const int* __restrict__ src, const int* __restrict__ dst,
    const int* __restrict__ bbase, int* __restrict__ bfill,
    int* __restrict__ pairs) {
    __shared__ int cnt[256];
    __shared__ int incl[256];
    __shared__ int lfill[256];
    __shared__ int rung[256];
    __shared__ int buf[4096];
    __shared__ unsigned char bk[4096];
    int t = threadIdx.x;
    cnt[t] = 0;
    lfill[t] = 0;
    __syncthreads();
    int base = blockIdx.x * 4096 + t * 16;
#pragma unroll
    for (int j = 0; j < 4; ++j) {
        int e = base + j * 4;
        if (e < NE) {
            int4 d = *(const int4*)(dst + e);
            atomicAdd(&cnt[d.x >> 8], 1);
            atomicAdd(&cnt[d.y >> 8], 1);
            atomicAdd(&cnt[d.z >> 8], 1);
            atomicAdd(&cnt[d.w >> 8], 1);
        }
    }
    __syncthreads();
    incl[t] = cnt[t];
    __syncthreads();
    LDS_SCAN256(incl, t);
    int c = cnt[t];
    if (t < NBUK && c > 0) rung[t] = bbase[t] + atomicAdd(&bfill[t], c);
    __syncthreads();
#pragma unroll
    for (int j = 0; j < 4; ++j) {
        int e = base + j * 4;
        if (e < NE) {
            int4 s4 = *(const int4*)(src + e);
            int4 d4 = *(const int4*)(dst + e);
            int ss[4] = {s4.x, s4.y, s4.z, s4.w};
            int dd[4] = {d4.x, d4.y, d4.z, d4.w};
#pragma unroll
            for (int q = 0; q < 4; ++q) {
                int k = dd[q] >> 8;
                int p = (incl[k] - cnt[k]) + atomicAdd(&lfill[k], 1);
                buf[p] = ((dd[q] & 255) << 24) | ss[q];
                bk[p] = (unsigned char)k;
            }
        }
    }
    __syncthreads();
    int n = min(4096, NE - blockIdx.x * 4096);
    for (int i = t; i < n; i += 256) {
        int k = bk[i];
        pairs[rung[k] + (i - (incl[k] - cnt[k]))] = buf[i];
    }
}

__global__ __launch_bounds__(256) void build_csr(
    const int* __restrict__ pairs, const int* __restrict__ bbase,
    int* __restrict__ rowptr, float* __restrict__ invcnt,
    int* __restrict__ csr_src) {
    __shared__ int cnt[256];
    __shared__ int incl[256];
    __shared__ int lfill[256];
    __shared__ int sbuf[BCAP];
    int b = blockIdx.x, t = threadIdx.x;
    int pbeg = bbase[b], pend = bbase[b + 1];
    int sz = pend - pbeg;
    cnt[t] = 0;
    lfill[t] = 0;
    __syncthreads();
    for (int i = t; i < sz; i += 256)
        atomicAdd(&cnt[(unsigned)pairs[pbeg + i] >> 24], 1);
    __syncthreads();
    incl[t] = cnt[t];
    __syncthreads();
    LDS_SCAN256(incl, t);
    int node = b * 256 + t;
    int c = cnt[t];
    if (node < NN) {
        rowptr[node] = pbeg + incl[t] - c;
        invcnt[node] = 1.0f / (float)(c > 0 ? c : 1);
    }
    if (sz <= BCAP) {
        for (int i = t; i < sz; i += 256) {
            int pr = pairs[pbeg + i];
            int ld = (unsigned)pr >> 24;
            sbuf[(incl[ld] - cnt[ld]) + atomicAdd(&lfill[ld], 1)] = pr & 0xFFFFFF;
        }
        __syncthreads();
        for (int i = t; i < sz; i += 256) csr_src[pbeg + i] = sbuf[i];
    } else {  // safety fallback
        for (int i = t; i < sz; i += 256) {
            int pr = pairs[pbeg + i];
            int ld = (unsigned)pr >> 24;
            csr_src[pbeg + (incl[ld] - cnt[ld]) + atomicAdd(&lfill[ld], 1)] = pr & 0xFFFFFF;
        }
    }
}

// ---------------- prep: zero meta + pack weights + x -> bf16 into A0 h-half ----------------

__device__ __forceinline__ void pack_one(const float* Wl, const float* Wr, int D,
                                         unsigned short* Wpk, int i) {
    int j = i & 7;
    int lane = (i >> 3) & 63;
    int ct = (i >> 9) & 7;
    int ks = i >> 12;
    int k = ks * 32 + ((lane >> 4) << 3) + j;
    int c = ct * 16 + (lane & 15);
    float v = (k < D) ? Wl[c * D + k] : Wr[c * D + (k - D)];
    Wpk[i] = f2bf(v);
}

#define PACK_BLOCKS 320   // 81920/256
#define CONV_BLOCKS 3125  // NN*16/256

__global__ __launch_bounds__(256) void prep(
    const float* __restrict__ Wl0, const float* __restrict__ Wr0,
    const float* __restrict__ Wl1, const float* __restrict__ Wr1,
    const float* __restrict__ Wl2, const float* __restrict__ Wr2,
    unsigned short* __restrict__ Wpk0, unsigned short* __restrict__ Wpk1,
    unsigned short* __restrict__ Wpk2,
    const float* __restrict__ x, unsigned short* __restrict__ A0,
    int* __restrict__ meta) {
    const int S0 = 2 * DIN * HD;   // 16384
    const int S12 = 2 * HD * HD;   // 32768
    int b = blockIdx.x;
    int t = threadIdx.x;
    if (b < PACK_BLOCKS) {
        int i = b * 256 + t;
        if (i < S0) { pack_one(Wl0, Wr0, DIN, Wpk0, i); return; }
        int j = i - S0;
        if (j < S12) { pack_one(Wl1, Wr1, HD, Wpk1, j); return; }
        int m = j - S12;
        if (m < S12) pack_one(Wl2, Wr2, HD, Wpk2, m);
        return;
    }
    if (b < PACK_BLOCKS + CONV_BLOCKS) {
        // x f32 [NN][64] -> bf16 into A0[:, 64:128] (row stride 128 shorts)
        int i = (b - PACK_BLOCKS) * 256 + t;   // < NN*16
        int row = i >> 4, c4 = i & 15;
        float4 v = ((const float4*)(x + (size_t)row * DIN))[c4];
        us4 o = {f2bf(v.x), f2bf(v.y), f2bf(v.z), f2bf(v.w)};
        *(us4*)(A0 + (size_t)row * 128 + 64 + c4 * 4) = o;
        return;
    }
    // last block: zero meta (bcnt[256] + bfill[256]) — 256 threads cover 512 ints
    meta[t] = 0;
    meta[t + 256] = 0;
}

// ---------------- gather-mean layer 0: half-wave per node, predicated 4-deep pipeline ----------------
// 8 nodes/block; 32 lanes/node = 4 edge-groups x 8 ch-lanes (us8 = 64ch).

__global__ __launch_bounds__(256) void gather_mean_x(
    const int* __restrict__ rowptr, const int* __restrict__ csr_src,
    const float* __restrict__ invcnt, unsigned short* __restrict__ A0) {
    int tid = threadIdx.x;
    int n = blockIdx.x * 8 + (tid >> 5);
    int c8 = tid & 7;
    int eg = (tid >> 3) & 3;
    int beg = rowptr[n], end = rowptr[n + 1];
    float acc[8] = {};
    const unsigned short* hb = A0 + 64 + (size_t)c8 * 8;
    for (int e = beg + eg; e < end; e += 16) {  // predicated 4-deep pipeline
        int e1 = e + 4, e2 = e + 8, e3 = e + 12;
        float w1 = (e1 < end) ? 1.f : 0.f;
        float w2 = (e2 < end) ? 1.f : 0.f;
        float w3 = (e3 < end) ? 1.f : 0.f;
        int i0 = csr_src[e];
        int i1 = csr_src[(e1 < end) ? e1 : e];
        int i2 = csr_src[(e2 < end) ? e2 : e];
        int i3 = csr_src[(e3 < end) ? e3 : e];
        us8 v0 = *(const us8*)(hb + (size_t)i0 * 128);
        us8 v1 = *(const us8*)(hb + (size_t)i1 * 128);
        us8 v2 = *(const us8*)(hb + (size_t)i2 * 128);
        us8 v3 = *(const us8*)(hb + (size_t)i3 * 128);
#pragma unroll
        for (int j = 0; j < 8; ++j) {
            float s = fmaf(bf2f(v1[j]), w1, bf2f(v0[j]));
            s = fmaf(bf2f(v2[j]), w2, s);
            s = fmaf(bf2f(v3[j]), w3, s);
            acc[j] += s;
        }
    }
#pragma unroll
    for (int j = 0; j < 8; ++j) {
        acc[j] += __shfl_xor(acc[j], 8, 64);
        acc[j] += __shfl_xor(acc[j], 16, 64);
    }
    if (eg == 0) {
        float ic = invcnt[n];
        us8 o;
#pragma unroll
        for (int j = 0; j < 8; ++j) o[j] = f2bf(acc[j] * ic);
        *(us8*)(A0 + (size_t)n * 128 + c8 * 8) = o;
    }
}

// ---------------- gather-mean layers 1,2: wave per node, predicated 4-deep pipeline ----------------
// 4 nodes/block; 64 lanes/node = 4 edge-groups x 16 ch-lanes (us8 = 128ch).

__global__ __launch_bounds__(256) void gather_mean_h(
    const unsigned short* __restrict__ A12, const int* __restrict__ rowptr,
    const int* __restrict__ csr_src, const float* __restrict__ invcnt,
    unsigned short* __restrict__ Am) {
    int tid = threadIdx.x;
    int n = blockIdx.x * 4 + (tid >> 6);
    int lane = tid & 63;
    int c8 = lane & 15;
    int eg = lane >> 4;
    int beg = rowptr[n], end = rowptr[n + 1];
    float acc[8] = {};
    const unsigned short* hb = A12 + 128 + (size_t)c8 * 8;
    for (int e = beg + eg; e < end; e += 16) {  // predicated 4-deep pipeline
        int e1 = e + 4, e2 = e + 8, e3 = e + 12;
        float w1 = (e1 < end) ? 1.f : 0.f;
        float w2 = (e2 < end) ? 1.f : 0.f;
        float w3 = (e3 < end) ? 1.f : 0.f;
        int i0 = csr_src[e];
        int i1 = csr_src[(e1 < end) ? e1 : e];
        int i2 = csr_src[(e2 < end) ? e2 : e];
        int i3 = csr_src[(e3 < end) ? e3 : e];
        us8 v0 = *(const us8*)(hb + (size_t)i0 * 256);
        us8 v1 = *(const us8*)(hb + (size_t)i1 * 256);
        us8 v2 = *(const us8*)(hb + (size_t)i2 * 256);
        us8 v3 = *(const us8*)(hb + (size_t)i3 * 256);
#pragma unroll
        for (int j = 0; j < 8; ++j) {
            float s = fmaf(bf2f(v1[j]), w1, bf2f(v0[j]));
            s = fmaf(bf2f(v2[j]), w2, s);
            s = fmaf(bf2f(v3[j]), w3, s);
            acc[j] += s;
        }
    }
#pragma unroll
    for (int j = 0; j < 8; ++j) {
        acc[j] += __shfl_xor(acc[j], 16, 64);
        acc[j] += __shfl_xor(acc[j], 32, 64);
    }
    if (eg == 0) {
        float ic = invcnt[n];
        us8 o;
#pragma unroll
        for (int j = 0; j < 8; ++j) o[j] = f2bf(acc[j] * ic);
        *(us8*)(Am + (size_t)n * 256 + c8 * 8) = o;
    }
}

// ---------------- fused MFMA GEMM + bias + L2 norm + (ReLU) ----------------

template <int K, bool RELU, bool F32OUT, bool BF16H>
__global__ __launch_bounds__(256) void linear_mfma(
    const unsigned short* __restrict__ A, const unsigned short* __restrict__ Wpk,
    const float* __restrict__ bias, float* __restrict__ outF,
    unsigned short* __restrict__ Hn /* h-part base (stride 256) */) {
    constexpr int NK = K / 32;
    __shared__ float rsum[2][32];
    int tid = threadIdx.x;
    int lane = tid & 63, w = tid >> 6;
    int rg = w >> 1, cg = w & 1;
    int r0 = blockIdx.x * 32 + rg * 16;
    int row_l = lane & 15, kb = lane >> 4;

    const unsigned short* Arow = A + (size_t)(r0 + row_l) * K + kb * 8;
    const unsigned short* Wp = Wpk + ((size_t)(cg * 4) * 64 + lane) * 8;

    f32x4 acc[4] = {{0.f, 0.f, 0.f, 0.f}, {0.f, 0.f, 0.f, 0.f},
                    {0.f, 0.f, 0.f, 0.f}, {0.f, 0.f, 0.f, 0.f}};
#pragma unroll
    for (int ks = 0; ks < NK; ++ks) {
        short8 a = *(const short8*)(Arow + ks * 32);
#pragma unroll
        for (int t = 0; t < 4; ++t) {
            short8 b = *(const short8*)(Wp + ((size_t)ks * 8 + t) * 64 * 8);
            acc[t] = __builtin_amdgcn_mfma_f32_16x16x32_bf16(a, b, acc[t], 0, 0, 0);
        }
    }

    float sq[4] = {0.f, 0.f, 0.f, 0.f};
#pragma unroll
    for (int t = 0; t < 4; ++t) {
        float bv = bias[cg * 64 + t * 16 + row_l];
#pragma unroll
        for (int r = 0; r < 4; ++r) {
            acc[t][r] += bv;
            sq[r] = fmaf(acc[t][r], acc[t][r], sq[r]);
        }
    }
#pragma unroll
    for (int off = 1; off < 16; off <<= 1)
#pragma unroll
        for (int r = 0; r < 4; ++r) sq[r] += __shfl_xor(sq[r], off, 64);

    if (row_l == 0) {
#pragma unroll
        for (int r = 0; r < 4; ++r) rsum[cg][rg * 16 + kb * 4 + r] = sq[r];
    }
    __syncthreads();  // also orders all A reads before the BF16H in-place writes

    int rbase = rg * 16 + kb * 4;
#pragma unroll
    for (int r = 0; r < 4; ++r) {
        int row = r0 + kb * 4 + r;
        if (row >= NN) continue;
        float n2 = rsum[0][rbase + r] + rsum[1][rbase + r];
        float inv = 1.0f / fmaxf(sqrtf(n2), 1e-12f);
#pragma unroll
        for (int t = 0; t < 4; ++t) {
            float v = acc[t][r] * inv;
            if (RELU) v = fmaxf(v, 0.f);
            int c = cg * 64 + t * 16 + row_l;
            if (F32OUT) outF[(size_t)row * HD + c] = v;
            if (BF16H) Hn[(size_t)row * 256 + c] = f2bf(v);
        }
    }
}

// ---------------- launch ----------------

static inline size_t align256(size_t x) { return (x + 255) & ~(size_t)255; }

extern "C" void kernel_launch(void* const* d_in, const int* in_sizes, int n_in,
                              void* d_out, int out_size, void* d_ws, size_t ws_size,
                              hipStream_t stream) {
    const float* x   = (const float*)d_in[0];
    const int*   ei  = (const int*)d_in[1];
    const float* Wl0 = (const float*)d_in[2];
    const float* bl0 = (const float*)d_in[3];
    const float* Wr0 = (const float*)d_in[4];
    const float* Wl1 = (const float*)d_in[5];
    const float* bl1 = (const float*)d_in[6];
    const float* Wr1 = (const float*)d_in[7];
    const float* Wl2 = (const float*)d_in[8];
    const float* bl2 = (const float*)d_in[9];
    const float* Wr2 = (const float*)d_in[10];

    const int* src = ei;
    const int* dst = ei + NE;

    // workspace carve-up
    char* p = (char*)d_ws;
    size_t off = 0;
    int* meta = (int*)(p + off);            off = align256(off + 512 * 4);
    int* bbase = (int*)(p + off);           off = align256(off + 256 * 4);
    int* rowptr = (int*)(p + off);          off = align256(off + (size_t)(NN + 1) * 4);
    int* csr_src = (int*)(p + off);         off = align256(off + (size_t)NE * 4);
    float* invcnt = (float*)(p + off);      off = align256(off + (size_t)NN * 4);
    int* pairs = (int*)(p + off);           off = align256(off + (size_t)NE * 4);
    unsigned short* A0 = (unsigned short*)(p + off);   off = align256(off + (size_t)NNP * 128 * 2);
    unsigned short* A12 = (unsigned short*)(p + off);  off = align256(off + (size_t)NNP * 256 * 2);
    unsigned short* Wpk0 = (unsigned short*)(p + off); off = align256(off + (size_t)2 * DIN * HD * 2);
    unsigned short* Wpk1 = (unsigned short*)(p + off); off = align256(off + (size_t)2 * HD * HD * 2);
    unsigned short* Wpk2 = (unsigned short*)(p + off); off = align256(off + (size_t)2 * HD * HD * 2);
    (void)ws_size; (void)n_in; (void)in_sizes; (void)out_size;

    int* bcnt = meta;
    int* bfill = meta + 256;
    float* out = (float*)d_out;

    // prep first (packs weights, converts x, zeroes meta — all independent of CSR)
    prep<<<PACK_BLOCKS + CONV_BLOCKS + 1, 256, 0, stream>>>(
        Wl0, Wr0, Wl1, Wr1, Wl2, Wr2, Wpk0, Wpk1, Wpk2, x, A0, meta);

    // CSR build: two-level LDS counting sort (packed pairs)
    bucket_count<<<SB, 256, 0, stream>>>(dst, bcnt);
    bucket_scan<<<1, 256, 0, stream>>>(bcnt, bbase, rowptr);
    bucket_scatter<<<SB, 256, 0, stream>>>(src, dst, bbase, bfill, pairs);
    build_csr<<<NBUK, 256, 0, stream>>>(pairs, bbase, rowptr, invcnt, csr_src);

    const int LG = NNP / 32;     // 1563
    const int GX = NN / 8;       // 6250
    const int GH = NN / 4;       // 12500

    // layer 0: gather bf16 x rows -> A0 mean part; GEMM K=128 -> h0 bf16 into A12[:,128:256]
    gather_mean_x<<<GX, 256, 0, stream>>>(rowptr, csr_src, invcnt, A0);
    linear_mfma<2 * DIN, true, false, true><<<LG, 256, 0, stream>>>(
        A0, Wpk0, bl0, nullptr, A12 + 128);

    // layer 1: gather h0 -> A12 mean part; GEMM K=256 -> h1 bf16 (row-exclusive in-place)
    gather_mean_h<<<GH, 256, 0, stream>>>(A12, rowptr, csr_src, invcnt, A12);
    linear_mfma<2 * HD, true, false, true><<<LG, 256, 0, stream>>>(
        A12, Wpk1, bl1, nullptr, A12 + 128);

    // layer 2: gather h1 -> A12 mean part; GEMM K=256 -> f32 d_out
    gather_mean_h<<<GH, 256, 0, stream>>>(A12, rowptr, csr_src, invcnt, A12);
    linear_mfma<2 * HD, false, true, false><<<LG, 256, 0, stream>>>(
        A12, Wpk2, bl2, out, nullptr);
}